// Round 2
// baseline (409.523 us; speedup 1.0000x reference)
//
#include <hip/hip_runtime.h>

// ---------------------------------------------------------------------------
// TraceSemanticHandshakeV342: fused concat+LayerNorm+Linear+GELU+Linear+GELU
// b=4, m=256, h=64, d=256, CAT=1283.  Rows = 65536.
// R2: one block per (b,m,h-half): M=32 rows, N=256, K=1280 bf16 MFMA with LN
// folded into epilogue.  2048 blocks, double-buffered LDS (1 barrier/seg),
// register prefetch of next segment, v_perm bf16 packing, pk_fma stats.
// ---------------------------------------------------------------------------

typedef float  f32x4 __attribute__((ext_vector_type(4)));
typedef float  f32x2 __attribute__((ext_vector_type(2)));
typedef short  s16x8 __attribute__((ext_vector_type(8)));

// round-half-up bf16 pack (error <= 1 ulp vs RNE; threshold is ~0.075)
__device__ __forceinline__ unsigned pack_bf2(float lo, float hi) {
    unsigned a = __builtin_bit_cast(unsigned, hi) + 0x8000u;
    unsigned b = __builtin_bit_cast(unsigned, lo) + 0x8000u;
    return __builtin_amdgcn_perm(a, b, 0x07060302u);  // {a.b3,a.b2,b.b3,b.b2}
}
__device__ __forceinline__ unsigned short f2bf(float f) {
    return (unsigned short)((__builtin_bit_cast(unsigned, f) + 0x8000u) >> 16);
}
// tanh-form GELU: max err ~4e-4 vs erf-GELU.
__device__ __forceinline__ float gelu_t(float x) {
    float u2 = 1.5957691216057308f * x + 0.07135481627f * (x * x * x);
    float e  = __expf(u2);
    float r  = __builtin_amdgcn_rcpf(e + 1.0f);
    return x - x * r;
}

// ---------------------------------------------------------------------------
// Prep: Sg[n]=sum_k gamma_k*W1[k,n], Sb[n]=sum_k beta_k*W1[k,n] (k<1280),
// W1T bf16 [256][1280] gamma-folded, W2T bf16 [256][256].
// ---------------------------------------------------------------------------
__global__ void __launch_bounds__(256)
prep_k(const float* __restrict__ W1, const float* __restrict__ W2,
       const float* __restrict__ gamma, const float* __restrict__ beta,
       float* __restrict__ Sg, float* __restrict__ Sb,
       short* __restrict__ w1t, short* __restrict__ w2t)
{
    __shared__ float tile[32][33];
    const int blk = blockIdx.x;
    const int tx = threadIdx.x & 31, ty = threadIdx.x >> 5;
    if (blk < 320) {
        const int kt = blk >> 3, nt = blk & 7;
#pragma unroll
        for (int j = 0; j < 4; ++j) {
            int kl = ty + 8 * j, k = kt * 32 + kl;
            tile[kl][tx] = gamma[k] * W1[k * 256 + nt * 32 + tx];
        }
        __syncthreads();
#pragma unroll
        for (int j = 0; j < 4; ++j) {
            int nl = ty + 8 * j, n = nt * 32 + nl;
            w1t[n * 1280 + kt * 32 + tx] = (short)f2bf(tile[tx][nl]);
        }
    } else if (blk < 384) {
        const int b2 = blk - 320;
        const int kt = b2 >> 3, nt = b2 & 7;
#pragma unroll
        for (int j = 0; j < 4; ++j) {
            int kl = ty + 8 * j, k = kt * 32 + kl;
            tile[kl][tx] = W2[k * 256 + nt * 32 + tx];
        }
        __syncthreads();
#pragma unroll
        for (int j = 0; j < 4; ++j) {
            int nl = ty + 8 * j, n = nt * 32 + nl;
            w2t[n * 256 + kt * 32 + tx] = (short)f2bf(tile[tx][nl]);
        }
    } else {
        const int kb = (blk - 384) * 32;
        const int n  = threadIdx.x;
        float sg = 0.f, sb = 0.f;
#pragma unroll
        for (int j = 0; j < 32; ++j) {
            int k = kb + j;
            float w = W1[k * 256 + n];
            sg += gamma[k] * w;
            sb += beta[k]  * w;
        }
        atomicAdd(&Sg[n], sg);
        atomicAdd(&Sb[n], sb);
    }
}

// ---------------------------------------------------------------------------
// Main: grid 2048, block 256 (4 waves).  Wave wv owns cols [wv*64, wv*64+64);
// 2 M-tiles x 4 N-tiles of 16x16x32 MFMA.  LDS: 2 x (32 rows x 256 bf16)
// double buffer, 16B-chunk XOR swizzle (chunk ^= row&7).
// ---------------------------------------------------------------------------
__global__ void __launch_bounds__(256, 3)
fused_main(const float* __restrict__ token, const float* __restrict__ step,
           const float* __restrict__ dyn,   const float* __restrict__ sem,
           const float* __restrict__ trace, const float* __restrict__ rel,
           const float* __restrict__ vis,   const float* __restrict__ gamma,
           const float* __restrict__ beta,  const float* __restrict__ W1,
           const float* __restrict__ b1v,   const float* __restrict__ b2v,
           const float* __restrict__ Sg,    const float* __restrict__ Sb,
           const short* __restrict__ w1t,   const short* __restrict__ w2t,
           float* __restrict__ out)
{
    __shared__ uint4 As[2][32 * 32];              // 2 x 16 KB
    __shared__ float rsum1[32], rsum2[32];
    __shared__ float mr_s[32], rs_s[32], t0s[32], t1s[32], t2s[32];

    const int t    = threadIdx.x;
    const int bm2  = blockIdx.x;
    const int bm   = bm2 >> 1;            // (b,m)
    const int row0 = (bm2 & 1) * 32;      // h offset
    const int b_i  = bm >> 8;
    const int lane = t & 63;
    const int wv   = t >> 6;
    const int l15  = lane & 15;
    const int q    = lane >> 4;
    const int n0   = wv * 64;

    // staging role: 8 threads per row, 32 f32 each
    const int sr = t >> 3;
    const int sq = t & 7;

    const float* srcs[5];
    srcs[0] = token + bm * 256 + sq * 32;                      // h-broadcast
    srcs[1] = step  + (b_i * 64 + row0 + sr) * 256 + sq * 32;  // m-broadcast
    srcs[2] = dyn   + (bm * 64 + row0 + sr) * 256 + sq * 32;
    srcs[3] = sem   + (bm * 64 + row0 + sr) * 256 + sq * 32;
    srcs[4] = trace + (bm * 64 + row0 + sr) * 256 + sq * 32;

    f32x4 acc[2][4];
#pragma unroll
    for (int i = 0; i < 2; ++i)
#pragma unroll
        for (int j = 0; j < 4; ++j)
            acc[i][j] = (f32x4){0.f, 0.f, 0.f, 0.f};

    f32x2 s1v = (f32x2){0.f, 0.f}, s2v = (f32x2){0.f, 0.f};

    float4 pf[8];
    {
        const float4* s4 = (const float4*)srcs[0];
#pragma unroll
        for (int i = 0; i < 8; ++i) pf[i] = s4[i];
    }

#pragma unroll
    for (int seg = 0; seg < 5; ++seg) {
        uint4* buf = &As[seg & 1][0];
        // convert + stats + LDS store of current segment (from registers)
#pragma unroll
        for (int i = 0; i < 4; ++i) {
            float4 a = pf[2 * i], b = pf[2 * i + 1];
            f32x2 p0 = (f32x2){a.x, a.y}, p1 = (f32x2){a.z, a.w};
            f32x2 p2 = (f32x2){b.x, b.y}, p3 = (f32x2){b.z, b.w};
            s1v += (p0 + p1) + (p2 + p3);
            s2v += p0 * p0; s2v += p1 * p1; s2v += p2 * p2; s2v += p3 * p3;
            uint4 p;
            p.x = pack_bf2(a.x, a.y);
            p.y = pack_bf2(a.z, a.w);
            p.z = pack_bf2(b.x, b.y);
            p.w = pack_bf2(b.z, b.w);
            int chunk = (sq * 4 + i) ^ (sr & 7);
            buf[sr * 32 + chunk] = p;
        }
        // prefetch next segment while this one's MFMA runs
        if (seg < 4) {
            const float4* s4 = (const float4*)srcs[seg + 1];
#pragma unroll
            for (int i = 0; i < 8; ++i) pf[i] = s4[i];
        }
        __syncthreads();
        const short* wseg = w1t + seg * 256;
#pragma unroll
        for (int kc = 0; kc < 8; ++kc) {
            s16x8 bfr[4];
#pragma unroll
            for (int nt = 0; nt < 4; ++nt) {
                int n = n0 + nt * 16 + l15;
                bfr[nt] = *(const s16x8*)(wseg + n * 1280 + kc * 32 + q * 8);
            }
            s16x8 afr[2];
#pragma unroll
            for (int mt = 0; mt < 2; ++mt) {
                int m = mt * 16 + l15;
                int chunk = (kc * 4 + q) ^ (m & 7);
                afr[mt] = *(const s16x8*)&buf[m * 32 + chunk];
            }
#pragma unroll
            for (int mt = 0; mt < 2; ++mt)
#pragma unroll
                for (int nt = 0; nt < 4; ++nt)
                    acc[mt][nt] = __builtin_amdgcn_mfma_f32_16x16x32_bf16(
                        afr[mt], bfr[nt], acc[mt][nt], 0, 0, 0);
        }
    }

    // ---- per-row LN stats over 1283 ---------------------------------------
    float s1 = s1v.x + s1v.y, s2 = s2v.x + s2v.y;
    s1 += __shfl_xor(s1, 1); s1 += __shfl_xor(s1, 2); s1 += __shfl_xor(s1, 4);
    s2 += __shfl_xor(s2, 1); s2 += __shfl_xor(s2, 2); s2 += __shfl_xor(s2, 4);
    if (sq == 0) { rsum1[sr] = s1; rsum2[sr] = s2; }
    __syncthreads();
    if (t < 32) {
        int g = bm * 64 + row0 + t;
        float x0 = rel[g * 2 + 0];
        float x1 = rel[g * 2 + 1];
        float x2 = vis[g];
        float S1 = rsum1[t] + x0 + x1 + x2;
        float S2 = rsum2[t] + x0 * x0 + x1 * x1 + x2 * x2;
        const float inv = 1.0f / 1283.0f;
        float mu  = S1 * inv;
        float var = S2 * inv - mu * mu;
        float rs  = rsqrtf(var + 1e-5f);
        rs_s[t] = rs;
        mr_s[t] = mu * rs;
        t0s[t] = (x0 - mu) * rs * gamma[1280] + beta[1280];
        t1s[t] = (x1 - mu) * rs * gamma[1281] + beta[1281];
        t2s[t] = (x2 - mu) * rs * gamma[1282] + beta[1282];
    }
    __syncthreads();

    // ---- epilogue 1: LN fixup + tail + bias + GELU -> y1 bf16 in As[1] ----
    unsigned short* y16 = (unsigned short*)&As[1][0];
#pragma unroll
    for (int nt = 0; nt < 4; ++nt) {
        int n = n0 + nt * 16 + l15;
        float sg  = Sg[n];
        float sbb = Sb[n] + b1v[n];
        float wt0 = W1[1280 * 256 + n];
        float wt1 = W1[1281 * 256 + n];
        float wt2 = W1[1282 * 256 + n];
#pragma unroll
        for (int mt = 0; mt < 2; ++mt) {
#pragma unroll
            for (int r4 = 0; r4 < 4; ++r4) {
                int r = mt * 16 + q * 4 + r4;
                float base = fmaf(t0s[r], wt0, sbb);
                base = fmaf(t1s[r], wt1, base);
                base = fmaf(t2s[r], wt2, base);
                float v = fmaf(rs_s[r], acc[mt][nt][r4],
                               fmaf(-mr_s[r], sg, base));
                v = gelu_t(v);
                int chunk = (n >> 3) ^ (r & 7);
                y16[(r * 32 + chunk) * 8 + (n & 7)] = f2bf(v);
            }
        }
    }
    __syncthreads();

    // ---- GEMM2: y1 (32x256 bf16, As[1]) @ W2T ------------------------------
    f32x4 acc2[2][4];
#pragma unroll
    for (int i = 0; i < 2; ++i)
#pragma unroll
        for (int j = 0; j < 4; ++j)
            acc2[i][j] = (f32x4){0.f, 0.f, 0.f, 0.f};

    const uint4* ybuf = &As[1][0];
#pragma unroll
    for (int kc = 0; kc < 8; ++kc) {
        s16x8 bfr[4];
#pragma unroll
        for (int nt = 0; nt < 4; ++nt) {
            int n = n0 + nt * 16 + l15;
            bfr[nt] = *(const s16x8*)(w2t + n * 256 + kc * 32 + q * 8);
        }
        s16x8 afr[2];
#pragma unroll
        for (int mt = 0; mt < 2; ++mt) {
            int m = mt * 16 + l15;
            int chunk = (kc * 4 + q) ^ (m & 7);
            afr[mt] = *(const s16x8*)&ybuf[m * 32 + chunk];
        }
#pragma unroll
        for (int mt = 0; mt < 2; ++mt)
#pragma unroll
            for (int nt = 0; nt < 4; ++nt)
                acc2[mt][nt] = __builtin_amdgcn_mfma_f32_16x16x32_bf16(
                    afr[mt], bfr[nt], acc2[mt][nt], 0, 0, 0);
    }

    // ---- epilogue 2: + b2, GELU, store ------------------------------------
#pragma unroll
    for (int nt = 0; nt < 4; ++nt) {
        int n = n0 + nt * 16 + l15;
        float bb = b2v[n];
#pragma unroll
        for (int mt = 0; mt < 2; ++mt)
#pragma unroll
            for (int r4 = 0; r4 < 4; ++r4) {
                int r = mt * 16 + q * 4 + r4;
                int g = bm * 64 + row0 + r;
                out[g * 256 + n] = gelu_t(acc2[mt][nt][r4] + bb);
            }
    }
}

// ---------------------------------------------------------------------------
extern "C" void kernel_launch(void* const* d_in, const int* in_sizes, int n_in,
                              void* d_out, int out_size, void* d_ws, size_t ws_size,
                              hipStream_t stream) {
    const float* token = (const float*)d_in[0];
    const float* step  = (const float*)d_in[1];
    const float* dyn   = (const float*)d_in[2];
    const float* sem   = (const float*)d_in[3];
    const float* trace = (const float*)d_in[4];
    const float* rel   = (const float*)d_in[5];
    const float* vis   = (const float*)d_in[6];
    const float* gamma = (const float*)d_in[7];
    const float* beta  = (const float*)d_in[8];
    const float* W1    = (const float*)d_in[9];
    const float* b1    = (const float*)d_in[10];
    const float* W2    = (const float*)d_in[11];
    const float* b2    = (const float*)d_in[12];

    float* Sg  = (float*)d_ws;
    float* Sb  = Sg + 256;
    short* w1t = (short*)((char*)d_ws + 2048);
    short* w2t = w1t + 1280 * 256;
    float* out = (float*)d_out;

    hipMemsetAsync(d_ws, 0, 2048, stream);
    hipLaunchKernelGGL(prep_k, dim3(424), dim3(256), 0, stream,
                       W1, W2, gamma, beta, Sg, Sb, w1t, w2t);
    hipLaunchKernelGGL(fused_main, dim3(2048), dim3(256), 0, stream,
                       token, step, dyn, sem, trace, rel, vis, gamma, beta,
                       W1, b1, b2, Sg, Sb, w1t, w2t, out);
}